// Round 4
// baseline (147.302 us; speedup 1.0000x reference)
//
#include <hip/hip_runtime.h>
#include <math.h>
#include <stdint.h>

#define C_DIM 1000
#define BIG   1.0e30f   // pad: u huge -> rcp underflows -> 0 in every sum (self-masking)

typedef float fx4 __attribute__((ext_vector_type(4)));

typedef __attribute__((address_space(1))) void g_void;   // global
typedef __attribute__((address_space(3))) void l_void;   // LDS

__device__ __forceinline__ float fexp2(float x) { return __builtin_amdgcn_exp2f(x); }
__device__ __forceinline__ float flog2(float x) { return __builtin_amdgcn_logf(x); }
__device__ __forceinline__ float frcp(float x)  { return __builtin_amdgcn_rcpf(x); }

// async global->LDS, 16B/lane, dest = uniform base + lane*16 (zero VGPR in flight)
__device__ __forceinline__ void gll16(const float* g, float* l) {
    __builtin_amdgcn_global_load_lds((g_void*)g, (l_void*)l, 16, 0, 0);
}

// pinned global load: issue point fixed (volatile), result regs forced ("=v")
__device__ __forceinline__ fx4 gload(const float* p) {
    fx4 r;
    asm volatile("global_load_dwordx4 %0, %1, off" : "=v"(r) : "v"(p));
    return r;
}

// phase-boundary waits: counted vmcnt, store-position-independent (counts only
// the >=8 later-phase LOADS; any outstanding store just adds harmless slack).
// "memory" clobber seals gll16/ds_read/stores into their phase.
__device__ __forceinline__ void wait8(fx4& a, fx4& b, fx4& c, fx4& d) {
    asm volatile("s_waitcnt vmcnt(8)" : "+v"(a), "+v"(b), "+v"(c), "+v"(d) :: "memory");
}
__device__ __forceinline__ void wait0(fx4& a, fx4& b, fx4& c, fx4& d) {
    asm volatile("s_waitcnt vmcnt(0)" : "+v"(a), "+v"(b), "+v"(c), "+v"(d) :: "memory");
}

// ---- DPP wave64 reductions (VALU pipe) ----
template <int CTRL, int RM>
__device__ __forceinline__ float dpp_add_term(float x) {
    int y = __builtin_amdgcn_update_dpp(0, __float_as_int(x), CTRL, RM, 0xf, true);
    return __int_as_float(y);
}
template <int CTRL, int RM>
__device__ __forceinline__ float dpp_max_term(float x) {
    int y = __builtin_amdgcn_update_dpp(__float_as_int(x), __float_as_int(x), CTRL, RM, 0xf, false);
    return __int_as_float(y);
}

#define DPP_SUM_CHAIN(x)                      \
    x += dpp_add_term<0x111, 0xf>(x);         \
    x += dpp_add_term<0x112, 0xf>(x);         \
    x += dpp_add_term<0x114, 0xf>(x);         \
    x += dpp_add_term<0x118, 0xf>(x);         \
    x += dpp_add_term<0x142, 0xa>(x);         \
    x += dpp_add_term<0x143, 0xc>(x);

__device__ __forceinline__ float bcast63(float x) {
    return __int_as_float(__builtin_amdgcn_readlane(__float_as_int(x), 63));
}

__device__ __forceinline__ float wave_sum(float x) {
    DPP_SUM_CHAIN(x)
    return bcast63(x);
}

__device__ __forceinline__ float wave_max(float x) {
    x = fmaxf(x, dpp_max_term<0x111, 0xf>(x));
    x = fmaxf(x, dpp_max_term<0x112, 0xf>(x));
    x = fmaxf(x, dpp_max_term<0x114, 0xf>(x));
    x = fmaxf(x, dpp_max_term<0x118, 0xf>(x));
    x = fmaxf(x, dpp_max_term<0x142, 0xa>(x));
    x = fmaxf(x, dpp_max_term<0x143, 0xc>(x));
    return bcast63(x);
}

// transform 16 logits -> bb[k] = -0.2*a[k]; returns lane-local max of a
__device__ __forceinline__ float tr16(const fx4 x0, const fx4 x1,
                                      const fx4 x2, const fx4 x3,
                                      float bb[16])
{
    bb[0]=-0.2f*x0.x;  bb[1]=-0.2f*x0.y;  bb[2]=-0.2f*x0.z;  bb[3]=-0.2f*x0.w;
    bb[4]=-0.2f*x1.x;  bb[5]=-0.2f*x1.y;  bb[6]=-0.2f*x1.z;  bb[7]=-0.2f*x1.w;
    bb[8]=-0.2f*x2.x;  bb[9]=-0.2f*x2.y;  bb[10]=-0.2f*x2.z; bb[11]=-0.2f*x2.w;
    bb[12]=-0.2f*x3.x; bb[13]=-0.2f*x3.y; bb[14]=-0.2f*x3.z; bb[15]=-0.2f*x3.w;
    float m0 = fmaxf(fmaxf(x0.x, x0.y), fmaxf(x0.z, x0.w));
    float m1 = fmaxf(fmaxf(x1.x, x1.y), fmaxf(x1.z, x1.w));
    float m2 = fmaxf(fmaxf(x2.x, x2.y), fmaxf(x2.z, x2.w));
    float m3 = fmaxf(fmaxf(x3.x, x3.y), fmaxf(x3.z, x3.w));
    return fmaxf(fmaxf(m0, m1), fmaxf(m2, m3));
}

// hot-class dot against bb (targets are raw one-hot {0,1}; result = -0.2 * a_hot)
__device__ __forceinline__ float dot16(const fx4 t0, const fx4 t1,
                                       const fx4 t2, const fx4 t3,
                                       const float bb[16])
{
    float s = 0.0f;
    s = fmaf(t0.x, bb[0],  s); s = fmaf(t0.y, bb[1],  s);
    s = fmaf(t0.z, bb[2],  s); s = fmaf(t0.w, bb[3],  s);
    s = fmaf(t1.x, bb[4],  s); s = fmaf(t1.y, bb[5],  s);
    s = fmaf(t1.z, bb[6],  s); s = fmaf(t1.w, bb[7],  s);
    s = fmaf(t2.x, bb[8],  s); s = fmaf(t2.y, bb[9],  s);
    s = fmaf(t2.z, bb[10], s); s = fmaf(t2.w, bb[11], s);
    s = fmaf(t3.x, bb[12], s); s = fmaf(t3.y, bb[13], s);
    s = fmaf(t3.z, bb[14], s); s = fmaf(t3.w, bb[15], s);
    return s;
}

// transform + LDS-target dot for one row (X regs die here)
__device__ __forceinline__ void prep(fx4 X0, fx4 X1, fx4 X2, fx4 X3,
                                     const float* lt, int ol, bool m3,
                                     float bb[16], float& mx, float& ah)
{
    X3 = m3 ? X3 : (fx4){-BIG, -BIG, -BIG, -BIG};
    mx = tr16(X0, X1, X2, X3, bb);
    fx4 v0 = *(const fx4*)(lt + ol);
    fx4 v1 = *(const fx4*)(lt + 256 + ol);
    fx4 v2 = *(const fx4*)(lt + 512 + ol);
    fx4 v3 = *(const fx4*)(lt + 768 + ol);
    v3 = m3 ? v3 : (fx4){0.f, 0.f, 0.f, 0.f};
    ah = dot16(v0, v1, v2, v3, bb);
}

// issue one row's 8 loads: 4 pinned x-loads -> regs, 4 gll16 targets -> LDS
__device__ __forceinline__ void issue_row(const float* in_r, const float* tg_r,
                                          int ol, int o3, float* lt,
                                          fx4& X0, fx4& X1, fx4& X2, fx4& X3)
{
    X0 = gload(in_r + ol);
    X1 = gload(in_r + 256 + ol);
    X2 = gload(in_r + 512 + ol);
    X3 = gload(in_r + o3);
    gll16(tg_r + ol,       lt);
    gll16(tg_r + 256 + ol, lt + 256);
    gll16(tg_r + 512 + ol, lt + 512);
    gll16(tg_r + o3,       lt + 768);
}

// full per-row pipeline after transform: reductions + 2 FP sweeps + Newton/loss sweep
__device__ __forceinline__ void row_core(const float bb[16], float mxl, float ahbl,
                                         float* __restrict__ row_out, int row, int lane,
                                         bool st, float C0, float E_off, float dE)
{
    const float mu  = wave_max(mxl);
    const float ahb = wave_sum(ahbl);
    const float g   = 0.2f * mu;
    const float hb  = ahb + g;          // == -0.2*(a_hot - mu) up to 1-2 ulp

    // ---- sweep 1: FP at lam=1 ----
    const float c1 = 1.0f + g;
    float s = 0.0f;
    #pragma unroll
    for (int k = 0; k < 16; ++k) {
        float u = bb[k] + c1;
        float u2 = u * u;
        s += frcp(u2 * u2 * u);
    }
    s = wave_sum(s);
    const float lam = fexp2(-0.2f * flog2(s));

    // ---- sweep 2: FP at lam -> w = s^0.2 (below root; Newton-safe) ----
    const float c2 = fmaf(lam, g, 1.0f);
    s = 0.0f;
    #pragma unroll
    for (int k = 0; k < 16; ++k) {
        float u = fmaf(lam, bb[k], c2);
        float u2 = u * u;
        s += frcp(u2 * u2 * u);
    }
    s = wave_sum(s);
    const float w = fexp2(0.2f * flog2(s));

    // ---- sweep 3: merged Newton + loss sums, 2nd-order corrected to w+delta ----
    const float c3 = w + g;
    float S4 = 0.0f, S5 = 0.0f, S6 = 0.0f, S9 = 0.0f, S10 = 0.0f, S11 = 0.0f;
    #pragma unroll
    for (int k = 0; k < 16; ++k) {
        float r  = frcp(bb[k] + c3);
        float r2 = r * r;
        float r4 = r2 * r2;
        float r5 = r4 * r;
        float r9 = r4 * r5;
        S4  += r4;
        S5  += r5;
        S6  += r5 * r;
        S9  += r9;
        S10 += r5 * r5;
        S11 += r9 * r2;
    }
    DPP_SUM_CHAIN(S4)
    DPP_SUM_CHAIN(S5)
    DPP_SUM_CHAIN(S6)
    DPP_SUM_CHAIN(S9)
    DPP_SUM_CHAIN(S10)
    DPP_SUM_CHAIN(S11)
    S4 = bcast63(S4);  S5 = bcast63(S5);  S6 = bcast63(S6);
    S9 = bcast63(S9);  S10 = bcast63(S10); S11 = bcast63(S11);

    const float d   = (S5 - 1.0f) * 0.2f * frcp(S6);            // Newton step (~5e-3)
    const float w1  = w + d;
    const float d2  = d * d;
    const float S4c = S4 + fmaf(10.0f * d2, S6,  -4.0f * d * S5);   // S4(w1) + O(d^3)
    const float S9c = S9 + fmaf(45.0f * d2, S11, -9.0f * d * S10);  // S9(w1) + O(d^3)
    const float rh  = frcp(w1 + hb);
    const float rh2 = rh * rh;
    const float rh4 = rh2 * rh2;

    const float loss = fmaf(-E_off, S4c,
                       fmaf(-dE, rh4,
                       fmaf(1.0f / 1.8f, S9c, C0)));
    if (st && lane == 0) row_out[row] = loss;
}

// 4 rows/wave, depth-2 rolling prefetch: wait row i -> transform -> issue row
// i+2 -> core row i. Every wave keeps ~8KB continuously in flight (copy-bench
// demand shape) -- the discriminating test of the ~2.9 TB/s read-delivery cap.
// 1024 blocks x 4 waves x 4 rows; (256,4) = 128 VGPR budget (peak live ~70);
// 32KB LDS/block -> 4 blocks/CU = one generation at 16 waves/CU.
__global__ __launch_bounds__(256, 4) void btll(
    const float* __restrict__ inputs, const float* __restrict__ targets,
    float* __restrict__ row_out, int n_rows,
    float C0, float E_off, float dE)
{
    const int lane = threadIdx.x & 63;
    const int wave = threadIdx.x >> 6;
    const int wid  = blockIdx.x * 4 + wave;
    const int rb   = wid * 4;
    if (rb >= n_rows) return;

    const int r0 = rb;
    const int r1 = min(rb + 1, n_rows - 1);
    const int r2 = min(rb + 2, n_rows - 1);
    const int r3 = min(rb + 3, n_rows - 1);
    const bool st1 = (rb + 1) < n_rows;
    const bool st2 = (rb + 2) < n_rows;
    const bool st3 = (rb + 3) < n_rows;

    __shared__ __align__(16) float ldsT[4][2][1024];
    float* lt0 = &ldsT[wave][0][0];
    float* lt1 = &ldsT[wave][1][0];

    const float* i0p = inputs  + (size_t)r0 * C_DIM;
    const float* t0p = targets + (size_t)r0 * C_DIM;
    const float* i1p = inputs  + (size_t)r1 * C_DIM;
    const float* t1p = targets + (size_t)r1 * C_DIM;
    const float* i2p = inputs  + (size_t)r2 * C_DIM;
    const float* t2p = targets + (size_t)r2 * C_DIM;
    const float* i3p = inputs  + (size_t)r3 * C_DIM;
    const float* t3p = targets + (size_t)r3 * C_DIM;

    const bool m3 = lane < 58;                  // 4th chunk tail mask (250 float4/row)
    const int  ol = 4 * lane;
    const int  o3 = m3 ? (768 + ol) : 0;        // clamped in-bounds offset for tail

    fx4 A0, A1, A2, A3, B0, B1, B2, B3;
    float bb[16], mx, ah;

    // ---- P0: rows 0,1 in flight (16 KB/wave) ----
    issue_row(i0p, t0p, ol, o3, lt0, A0, A1, A2, A3);
    issue_row(i1p, t1p, ol, o3, lt1, B0, B1, B2, B3);
    wait8(A0, A1, A2, A3);                      // 8 newer loads (row1) stay in flight

    // ---- P1: row0 compute, row2 loads stream underneath ----
    prep(A0, A1, A2, A3, lt0, ol, m3, bb, mx, ah);
    issue_row(i2p, t2p, ol, o3, lt0, A0, A1, A2, A3);   // lt0 fully read above
    row_core(bb, mx, ah, row_out, r0, lane, true, C0, E_off, dE);
    wait8(B0, B1, B2, B3);                      // row1 ready; row2's 8 still in flight

    // ---- P2: row1 compute, row3 loads stream underneath ----
    prep(B0, B1, B2, B3, lt1, ol, m3, bb, mx, ah);
    issue_row(i3p, t3p, ol, o3, lt1, B0, B1, B2, B3);
    row_core(bb, mx, ah, row_out, r1, lane, st1, C0, E_off, dE);
    wait8(A0, A1, A2, A3);                      // row2 ready; row3's 8 still in flight

    // ---- P3: row2 compute ----
    prep(A0, A1, A2, A3, lt0, ol, m3, bb, mx, ah);
    row_core(bb, mx, ah, row_out, r2, lane, st2, C0, E_off, dE);
    wait0(B0, B1, B2, B3);                      // drain row3 (+ pending stores)

    // ---- P4: row3 compute ----
    prep(B0, B1, B2, B3, lt1, ol, m3, bb, mx, ah);
    row_core(bb, mx, ah, row_out, r3, lane, st3, C0, E_off, dE);
}

__global__ __launch_bounds__(1024) void reduce_mean(
    const float* __restrict__ row_out, float* __restrict__ out, int n)
{
    __shared__ double sm[16];
    const int lane = threadIdx.x & 63;
    const int wv   = threadIdx.x >> 6;
    const int n4   = n >> 2;
    const float4* r4 = (const float4*)row_out;
    double s = 0.0;
    for (int i = threadIdx.x; i < n4; i += 1024) {
        float4 v = r4[i];
        s += (double)v.x + (double)v.y + (double)v.z + (double)v.w;
    }
    if (threadIdx.x == 0)
        for (int i = n4 << 2; i < n; ++i) s += (double)row_out[i];
    #pragma unroll
    for (int off = 32; off > 0; off >>= 1) s += __shfl_xor(s, off, 64);
    if (lane == 0) sm[wv] = s;
    __syncthreads();
    if (wv == 0) {
        double t = (lane < 16) ? sm[lane] : 0.0;
        #pragma unroll
        for (int off = 32; off > 0; off >>= 1) t += __shfl_xor(t, off, 64);
        if (lane == 0) out[0] = (float)(t / (double)n);
    }
}

extern "C" void kernel_launch(void* const* d_in, const int* in_sizes, int n_in,
                              void* d_out, int out_size, void* d_ws, size_t ws_size,
                              hipStream_t stream) {
    const float* inputs  = (const float*)d_in[0];
    const float* targets = (const float*)d_in[1];
    float* out = (float*)d_out;

    const int N = in_sizes[0] / C_DIM;
    float* row_out = (float*)d_ws;

    // Smoothed one-hot targets take 2 values; per-elem loss = F - E*r4 + r9/1.8.
    // Row sum = C0 - E_off*S4 - (E_on-E_off)*r4_hot + S9/1.8, C0 = 999*F_off + F_on.
    const double ls    = 0.05;
    const double c1g_d = 1.0 - (1000.0 / 999.0) * ls;
    const double c2_d  = ls / 999.0;
    const float  tp_on_f  = (float)c1g_d + (float)c2_d;
    const float  tp_off_f = (float)c2_d;
    const double tp_on  = (double)tp_on_f;
    const double tp_off = (double)tp_off_f;
    const double A_on  = (pow(tp_on  + 1e-8, 0.8) - 1.0) / 0.8;
    const double A_off = (pow(tp_off + 1e-8, 0.8) - 1.0) / 0.8;
    const double B_on  = pow(tp_on,  1.8);
    const double B_off = pow(tp_off, 1.8);
    const double E_on_d  = 1.25 * tp_on;
    const double E_off_d = 1.25 * tp_off;
    const double F_on_d  = tp_on  * A_on  + E_on_d  - B_on  / 1.8;
    const double F_off_d = tp_off * A_off + E_off_d - B_off / 1.8;
    const double C0_d    = (C_DIM - 1) * F_off_d + F_on_d;
    const double dE_d    = E_on_d - E_off_d;

    dim3 grid((N + 15) / 16);
    btll<<<grid, 256, 0, stream>>>(inputs, targets, row_out, N,
                                   (float)C0_d, (float)E_off_d, (float)dE_d);
    reduce_mean<<<1, 1024, 0, stream>>>(row_out, out, N);
}

// Round 5
// 143.333 us; speedup vs baseline: 1.0277x; 1.0277x over previous
//
#include <hip/hip_runtime.h>
#include <math.h>

#define C_DIM 1000
#define BIG   1.0e30f   // pad: u huge -> rcp underflows -> 0 in every sum (self-masking)

__device__ __forceinline__ float fexp2(float x) { return __builtin_amdgcn_exp2f(x); }
__device__ __forceinline__ float flog2(float x) { return __builtin_amdgcn_logf(x); }
__device__ __forceinline__ float frcp(float x)  { return __builtin_amdgcn_rcpf(x); }

// ---- DPP wave64 reductions (VALU pipe; ~10x lower latency than shfl/bpermute) ----
// sum: moved-in value 0 for invalid/masked lanes (bound_ctrl=1, old=0) -> add identity
template <int CTRL, int RM>
__device__ __forceinline__ float dpp_add_term(float x) {
    int y = __builtin_amdgcn_update_dpp(0, __float_as_int(x), CTRL, RM, 0xf, true);
    return __int_as_float(y);
}
// max: invalid/masked lanes keep old=x -> fmax identity
template <int CTRL, int RM>
__device__ __forceinline__ float dpp_max_term(float x) {
    int y = __builtin_amdgcn_update_dpp(__float_as_int(x), __float_as_int(x), CTRL, RM, 0xf, false);
    return __int_as_float(y);
}

#define DPP_SUM_CHAIN(x)                      \
    x += dpp_add_term<0x111, 0xf>(x);         \
    x += dpp_add_term<0x112, 0xf>(x);         \
    x += dpp_add_term<0x114, 0xf>(x);         \
    x += dpp_add_term<0x118, 0xf>(x);         \
    x += dpp_add_term<0x142, 0xa>(x);         \
    x += dpp_add_term<0x143, 0xc>(x);

__device__ __forceinline__ float bcast63(float x) {
    return __int_as_float(__builtin_amdgcn_readlane(__float_as_int(x), 63));
}

__device__ __forceinline__ float wave_sum(float x) {
    DPP_SUM_CHAIN(x)
    return bcast63(x);
}

__device__ __forceinline__ float wave_max(float x) {
    x = fmaxf(x, dpp_max_term<0x111, 0xf>(x));
    x = fmaxf(x, dpp_max_term<0x112, 0xf>(x));
    x = fmaxf(x, dpp_max_term<0x114, 0xf>(x));
    x = fmaxf(x, dpp_max_term<0x118, 0xf>(x));
    x = fmaxf(x, dpp_max_term<0x142, 0xa>(x));
    x = fmaxf(x, dpp_max_term<0x143, 0xc>(x));
    return bcast63(x);
}

// One wave per row; grid 4096 x 4 waves = 2 full-occupancy generations
// (gen-2 loads stream under gen-1 compute).
// Session-verified fastest structure: 44.6 us btll @ 2.94 TB/s delivered read BW
// == ~95% of the per-direction read-return ceiling (~3.15 TB/s; the 6.29 TB/s
// copy ceiling is FETCH+WRITE combined). R1-R4 proved duration is pinned by
// delivered read bytes: warm(L3)==cold(HBM) duration, and HW-enforced prefetch
// structures (gll16/asm vmcnt, R3-R4) all landed at 47-50 us with the same
// ~2.6-2.9 TB/s. 131 MB / ~3.1 TB/s ~= 43 us structural floor.
__global__ __launch_bounds__(256) void btll(
    const float* __restrict__ inputs, const float* __restrict__ targets,
    float* __restrict__ row_out, int n_rows,
    float C0, float E_off, float dE)
{
    const int lane = threadIdx.x & 63;
    const int wave = threadIdx.x >> 6;
    const int row  = blockIdx.x * 4 + wave;
    if (row >= n_rows) return;

    const float4* in4 = (const float4*)(inputs  + (size_t)row * C_DIM);
    const float4* tg4 = (const float4*)(targets + (size_t)row * C_DIM);
    const bool m3 = (lane + 192) < 250;   // only the 4th chunk needs tail masking

    // ---- issue all 8 coalesced 16B loads up front ----
    float4 x0 = in4[lane];
    float4 x1 = in4[lane + 64];
    float4 x2 = in4[lane + 128];
    float4 x3 = m3 ? in4[lane + 192] : make_float4(-BIG, -BIG, -BIG, -BIG);
    float4 t0 = tg4[lane];
    float4 t1 = tg4[lane + 64];
    float4 t2 = tg4[lane + 128];
    float4 t3 = m3 ? tg4[lane + 192] : make_float4(0.f, 0.f, 0.f, 0.f);

    float a[16];
    a[0]=x0.x; a[1]=x0.y; a[2]=x0.z; a[3]=x0.w;
    a[4]=x1.x; a[5]=x1.y; a[6]=x1.z; a[7]=x1.w;
    a[8]=x2.x; a[9]=x2.y; a[10]=x2.z; a[11]=x2.w;
    a[12]=x3.x; a[13]=x3.y; a[14]=x3.z; a[15]=x3.w;

    // hot-class logit (targets are raw one-hot {0,1}) + row max
    float ah = 0.0f;
    ah = fmaf(t0.x, a[0], ah);  ah = fmaf(t0.y, a[1], ah);
    ah = fmaf(t0.z, a[2], ah);  ah = fmaf(t0.w, a[3], ah);
    ah = fmaf(t1.x, a[4], ah);  ah = fmaf(t1.y, a[5], ah);
    ah = fmaf(t1.z, a[6], ah);  ah = fmaf(t1.w, a[7], ah);
    ah = fmaf(t2.x, a[8], ah);  ah = fmaf(t2.y, a[9], ah);
    ah = fmaf(t2.z, a[10], ah); ah = fmaf(t2.w, a[11], ah);
    ah = fmaf(t3.x, a[12], ah); ah = fmaf(t3.y, a[13], ah);
    ah = fmaf(t3.z, a[14], ah); ah = fmaf(t3.w, a[15], ah);

    float mu = a[0];
    #pragma unroll
    for (int k = 1; k < 16; ++k) mu = fmaxf(mu, a[k]);
    mu = wave_max(mu);
    ah = wave_sum(ah);

    float b[16];
    #pragma unroll
    for (int k = 0; k < 16; ++k) b[k] = -0.2f * (a[k] - mu);  // >= 0; pad -> ~2e29
    const float hb = -0.2f * (ah - mu);

    // ---- sweep 1: FP at lam=1 ----
    float s = 0.0f;
    #pragma unroll
    for (int k = 0; k < 16; ++k) {
        float u = 1.0f + b[k];
        float u2 = u * u;
        s += frcp(u2 * u2 * u);
    }
    s = wave_sum(s);
    const float lam = fexp2(-0.2f * flog2(s));

    // ---- sweep 2: FP at lam -> w0 = s^0.2 (below root; Newton-safe) ----
    s = 0.0f;
    #pragma unroll
    for (int k = 0; k < 16; ++k) {
        float u = fmaf(lam, b[k], 1.0f);
        float u2 = u * u;
        s += frcp(u2 * u2 * u);
    }
    s = wave_sum(s);
    const float w = fexp2(0.2f * flog2(s));

    // ---- sweep 3: merged Newton + loss sums, 2nd-order corrected to w+delta ----
    float S4 = 0.0f, S5 = 0.0f, S6 = 0.0f, S9 = 0.0f, S10 = 0.0f, S11 = 0.0f;
    #pragma unroll
    for (int k = 0; k < 16; ++k) {
        float r  = frcp(w + b[k]);
        float r2 = r * r;
        float r4 = r2 * r2;
        float r5 = r4 * r;
        float r9 = r4 * r5;
        S4  += r4;
        S5  += r5;
        S6  += r5 * r;
        S9  += r9;
        S10 += r5 * r5;
        S11 += r9 * r2;
    }
    DPP_SUM_CHAIN(S4)
    DPP_SUM_CHAIN(S5)
    DPP_SUM_CHAIN(S6)
    DPP_SUM_CHAIN(S9)
    DPP_SUM_CHAIN(S10)
    DPP_SUM_CHAIN(S11)
    S4 = bcast63(S4);  S5 = bcast63(S5);  S6 = bcast63(S6);
    S9 = bcast63(S9);  S10 = bcast63(S10); S11 = bcast63(S11);

    const float d   = (S5 - 1.0f) * 0.2f * frcp(S6);            // Newton step (~5e-3)
    const float w1  = w + d;
    const float d2  = d * d;
    const float S4c = S4 + fmaf(10.0f * d2, S6,  -4.0f * d * S5);   // S4(w1) + O(d^3)
    const float S9c = S9 + fmaf(45.0f * d2, S11, -9.0f * d * S10);  // S9(w1) + O(d^3)
    const float rh  = frcp(w1 + hb);
    const float rh2 = rh * rh;
    const float rh4 = rh2 * rh2;

    const float loss = fmaf(-E_off, S4c,
                       fmaf(-dE, rh4,
                       fmaf(1.0f / 1.8f, S9c, C0)));
    if (lane == 0) row_out[row] = loss;
}

__global__ __launch_bounds__(1024) void reduce_mean(
    const float* __restrict__ row_out, float* __restrict__ out, int n)
{
    __shared__ double sm[16];
    const int lane = threadIdx.x & 63;
    const int wv   = threadIdx.x >> 6;
    const int n4   = n >> 2;
    const float4* r4 = (const float4*)row_out;
    double s = 0.0;
    for (int i = threadIdx.x; i < n4; i += 1024) {
        float4 v = r4[i];
        s += (double)v.x + (double)v.y + (double)v.z + (double)v.w;
    }
    if (threadIdx.x == 0)
        for (int i = n4 << 2; i < n; ++i) s += (double)row_out[i];
    #pragma unroll
    for (int off = 32; off > 0; off >>= 1) s += __shfl_xor(s, off, 64);
    if (lane == 0) sm[wv] = s;
    __syncthreads();
    if (wv == 0) {
        double t = (lane < 16) ? sm[lane] : 0.0;
        #pragma unroll
        for (int off = 32; off > 0; off >>= 1) t += __shfl_xor(t, off, 64);
        if (lane == 0) out[0] = (float)(t / (double)n);
    }
}

extern "C" void kernel_launch(void* const* d_in, const int* in_sizes, int n_in,
                              void* d_out, int out_size, void* d_ws, size_t ws_size,
                              hipStream_t stream) {
    const float* inputs  = (const float*)d_in[0];
    const float* targets = (const float*)d_in[1];
    float* out = (float*)d_out;

    const int N = in_sizes[0] / C_DIM;
    float* row_out = (float*)d_ws;

    // Smoothed one-hot targets take 2 values; per-elem loss = F - E*r4 + r9/1.8.
    // Row sum = C0 - E_off*S4 - (E_on-E_off)*r4_hot + S9/1.8, C0 = 999*F_off + F_on.
    const double ls    = 0.05;
    const double c1g_d = 1.0 - (1000.0 / 999.0) * ls;
    const double c2_d  = ls / 999.0;
    const float  tp_on_f  = (float)c1g_d + (float)c2_d;
    const float  tp_off_f = (float)c2_d;
    const double tp_on  = (double)tp_on_f;
    const double tp_off = (double)tp_off_f;
    const double A_on  = (pow(tp_on  + 1e-8, 0.8) - 1.0) / 0.8;
    const double A_off = (pow(tp_off + 1e-8, 0.8) - 1.0) / 0.8;
    const double B_on  = pow(tp_on,  1.8);
    const double B_off = pow(tp_off, 1.8);
    const double E_on_d  = 1.25 * tp_on;
    const double E_off_d = 1.25 * tp_off;
    const double F_on_d  = tp_on  * A_on  + E_on_d  - B_on  / 1.8;
    const double F_off_d = tp_off * A_off + E_off_d - B_off / 1.8;
    const double C0_d    = (C_DIM - 1) * F_off_d + F_on_d;
    const double dE_d    = E_on_d - E_off_d;

    dim3 grid((N + 3) / 4);
    btll<<<grid, 256, 0, stream>>>(inputs, targets, row_out, N,
                                   (float)C0_d, (float)E_off_d, (float)dE_d);
    reduce_mean<<<1, 1024, 0, stream>>>(row_out, out, N);
}